// Round 4
// baseline (207.252 us; speedup 1.0000x reference)
//
#include <hip/hip_runtime.h>
#include <hip/hip_bf16.h>

// GaussianCodebook: out[b,s,c] = mean_d((x[b,s,d]-cb[d,c])^2)
//                 = x2[m] + c2[n] - (2/D) * dot(x[m,:], cb[:,n])
// B=8 S=4096 D=512 C=2048  -> GEMM M=32768 N=2048 K=512 (bf16 MFMA) + epilogue.
// R4 (= R3 + fixes): persistent-block GEMM (grid=256, 1 block/CU). Tile
//     256x128, BK=64, 8 waves (4Mx2N), double acc set: tile j computes into
//     set P while tile j-1's stores issue 2-per-phase from set ~P.
//     Fixes vs R3: STORE1 constexpr->const (compile), G1K0 11->7 (gate was
//     too LOOSE at hot-tile kt0: ops-after-B1 = 9 hot->hot, 7 cold->hot;
//     7 is strict-safe for both).

typedef __attribute__((ext_vector_type(8))) short bf16x8;
typedef __attribute__((ext_vector_type(4))) float f32x4;

#define M_ROWS 32768
#define K_DIM  512
#define N_COLS 2048

__device__ __forceinline__ unsigned short f2bf(float f) {
    unsigned int u = __float_as_uint(f);
    return (unsigned short)((u + 0x7fffu + ((u >> 16) & 1u)) >> 16);  // RNE
}

__device__ __forceinline__ void gload_lds16(const void* g, void* l) {
    __builtin_amdgcn_global_load_lds(
        (const __attribute__((address_space(1))) unsigned int*)g,
        (__attribute__((address_space(3))) unsigned int*)l,
        16, 0, 0);
}

// ---- prep_x: cast x f32 -> bf16, and x2[m] = mean_d x^2 ----
__global__ __launch_bounds__(256) void prep_x_kernel(const float* __restrict__ x,
                                                     unsigned short* __restrict__ xb,
                                                     float* __restrict__ x2) {
    const int wid = threadIdx.x >> 6;
    const int lane = threadIdx.x & 63;
    const int row = (blockIdx.x << 2) + wid;
    const float4* p4 = reinterpret_cast<const float4*>(x + (size_t)row * K_DIM);
    float4 v0 = p4[lane];
    float4 v1 = p4[lane + 64];
    float ss = v0.x*v0.x + v0.y*v0.y + v0.z*v0.z + v0.w*v0.w
             + v1.x*v1.x + v1.y*v1.y + v1.z*v1.z + v1.w*v1.w;
    union { unsigned short us[4]; uint2 u2; } pa, pb;
    pa.us[0] = f2bf(v0.x); pa.us[1] = f2bf(v0.y); pa.us[2] = f2bf(v0.z); pa.us[3] = f2bf(v0.w);
    pb.us[0] = f2bf(v1.x); pb.us[1] = f2bf(v1.y); pb.us[2] = f2bf(v1.z); pb.us[3] = f2bf(v1.w);
    uint2* dst = reinterpret_cast<uint2*>(xb + (size_t)row * K_DIM);
    dst[lane]      = pa.u2;
    dst[lane + 64] = pb.u2;
    #pragma unroll
    for (int off = 32; off; off >>= 1) ss += __shfl_xor(ss, off);
    if (lane == 0) x2[row] = ss * (1.0f / (float)K_DIM);
}

// ---- prep_cb: transpose cb [K=512][N=2048] f32 -> cbT [N][K] bf16, scaled by 2/D = 2^-8 ----
__global__ __launch_bounds__(256) void prep_cb_kernel(const float* __restrict__ cb,
                                                      unsigned short* __restrict__ cbT) {
    __shared__ float tile[32][65];
    const int k0 = blockIdx.x * 32;
    const int n0 = blockIdx.y * 64;
    const int tx = threadIdx.x & 63;
    const int ty = threadIdx.x >> 6;
    #pragma unroll
    for (int i = 0; i < 8; ++i) {
        const int k = ty + i * 4;
        tile[k][tx] = cb[(size_t)(k0 + k) * N_COLS + n0 + tx];
    }
    __syncthreads();
    const int kc = threadIdx.x & 31;
    const int nr = threadIdx.x >> 5;
    #pragma unroll
    for (int i = 0; i < 8; ++i) {
        const int n = nr + i * 8;
        cbT[(size_t)(n0 + n) * K_DIM + k0 + kc] = f2bf(tile[kc][n] * 0.00390625f);
    }
}

// ---- c2[n] = mean_k cb[k][n]^2 ----
__global__ __launch_bounds__(256) void c2_kernel(const float* __restrict__ cb,
                                                 float* __restrict__ c2) {
    __shared__ float p[4][64];
    const int t = threadIdx.x;
    const int nl = t & 63;
    const int kc = t >> 6;
    const int n = blockIdx.x * 64 + nl;
    float s = 0.0f;
    for (int k = kc * 128; k < kc * 128 + 128; ++k) {
        float v = cb[(size_t)k * N_COLS + n];
        s += v * v;
    }
    p[kc][nl] = s;
    __syncthreads();
    if (t < 64) {
        c2[blockIdx.x * 64 + t] =
            (p[0][t] + p[1][t] + p[2][t] + p[3][t]) * (1.0f / (float)K_DIM);
    }
}

// ======================= persistent 256x128 GEMM =======================
// LDS per dbuf: A0(256x32)=16KB @0, A1 @8192, B0(128x32)=8KB @16384, B1 @20480 (shorts)
#define A0OFF 0
#define A1OFF 8192
#define B0OFF 16384
#define B1OFF 20480

__device__ __forceinline__ void stage_halfA(const unsigned short* __restrict__ g,
                                            unsigned short* l, int wid, int lane) {
    #pragma unroll
    for (int i = 0; i < 2; ++i) {
        const int o16 = i * 512 + wid * 64 + lane;   // 1024 chunks of 16B
        const int row = o16 >> 2;                    // 256 rows, 64B/row
        const int sl  = (o16 & 3) ^ ((row >> 1) & 3);
        gload_lds16(g + (size_t)row * K_DIM + sl * 8, l + i * 4096 + wid * 512);
    }
}
__device__ __forceinline__ void stage_halfB(const unsigned short* __restrict__ g,
                                            unsigned short* l, int wid, int lane) {
    const int o16 = wid * 64 + lane;                 // 512 chunks
    const int row = o16 >> 2;                        // 128 rows
    const int sl  = (o16 & 3) ^ ((row >> 1) & 3);
    gload_lds16(g + (size_t)row * K_DIM + sl * 8, l + wid * 512);
}

__device__ __forceinline__ bf16x8 frag_ld(const unsigned short* h, int r, int lhi) {
    const int off = r * 32 + ((lhi ^ ((r >> 1) & 3)) << 3);
    return *reinterpret_cast<const bf16x8*>(&h[off]);
}

#define BAR()  do { asm volatile("" ::: "memory"); \
                    __builtin_amdgcn_s_barrier();  \
                    asm volatile("" ::: "memory"); } while (0)
#define GATE_(n) asm volatile("s_waitcnt vmcnt(" #n ")" ::: "memory")
#define GATE(n) GATE_(n)

#define STORE1(OACC, IDX)                                                      \
  { const int i_ = (IDX);                                                      \
    const int mf_ = i_ >> 4, nf_ = (i_ >> 2) & 3, jj_ = i_ & 3;                \
    outOld[(size_t)(mf_ * 16 + jj_) * N_COLS + nf_ * 16] =                     \
        x2v[mf_ * 4 + jj_] + c2o[nf_] - OACC[mf_][nf_][jj_]; }

#define MFMA8(ACCC, BASE)                                                      \
  _Pragma("unroll")                                                            \
  for (int nf_ = 0; nf_ < 4; ++nf_) {                                          \
    ACCC[(BASE)][nf_]     = __builtin_amdgcn_mfma_f32_16x16x32_bf16(a[(BASE)],     b[nf_], ACCC[(BASE)][nf_],     0, 0, 0); \
    ACCC[(BASE) + 1][nf_] = __builtin_amdgcn_mfma_f32_16x16x32_bf16(a[(BASE) + 1], b[nf_], ACCC[(BASE) + 1][nf_], 0, 0, 0); \
  }

// one BK=64 K-tile: 4 phases. Per phase: [stage next half][ds_read frags]
// [BAR][MFMA x8][2 stores of old tile][gate?][BAR]
#define KTILE(KT, ACCC, ACCO, DOST, G1N, G2N, DOG2, GA, GB, DOSTG)             \
  {                                                                            \
    const unsigned short* hA0_ = &smem[(KT) & 1][A0OFF];                       \
    const unsigned short* hA1_ = &smem[(KT) & 1][A1OFF];                       \
    const unsigned short* hB0_ = &smem[(KT) & 1][B0OFF];                       \
    const unsigned short* hB1_ = &smem[(KT) & 1][B1OFF];                       \
    unsigned short* nxt_ = smem[((KT) + 1) & 1];                               \
    /* phase 0 */                                                              \
    if (DOSTG) stage_halfA(GA, nxt_ + A0OFF, wid, lane);                       \
    a[0] = frag_ld(hA0_, wr64 +  0 + l15, lhi);                                \
    a[1] = frag_ld(hA0_, wr64 + 16 + l15, lhi);                                \
    _Pragma("unroll")                                                          \
    for (int nf_ = 0; nf_ < 4; ++nf_)                                          \
        b[nf_] = frag_ld(hB0_, wc64 + nf_ * 16 + l15, lhi);                    \
    BAR();                                                                     \
    __builtin_amdgcn_s_setprio(1);                                             \
    MFMA8(ACCC, 0);                                                            \
    __builtin_amdgcn_s_setprio(0);                                             \
    if (DOST) { STORE1(ACCO, (KT) * 8 + 0); STORE1(ACCO, (KT) * 8 + 1); }      \
    BAR();                                                                     \
    /* phase 1 */                                                              \
    if (DOSTG) stage_halfB(GB, nxt_ + B0OFF, wid, lane);                       \
    a[2] = frag_ld(hA0_, wr64 + 32 + l15, lhi);                                \
    a[3] = frag_ld(hA0_, wr64 + 48 + l15, lhi);                                \
    BAR();                                                                     \
    __builtin_amdgcn_s_setprio(1);                                             \
    MFMA8(ACCC, 2);                                                            \
    __builtin_amdgcn_s_setprio(0);                                             \
    if (DOST) { STORE1(ACCO, (KT) * 8 + 2); STORE1(ACCO, (KT) * 8 + 3); }      \
    GATE(G1N);                                                                 \
    BAR();                                                                     \
    /* phase 2 */                                                              \
    if (DOSTG) stage_halfA(GA + 32, nxt_ + A1OFF, wid, lane);                  \
    a[0] = frag_ld(hA1_, wr64 +  0 + l15, lhi);                                \
    a[1] = frag_ld(hA1_, wr64 + 16 + l15, lhi);                                \
    _Pragma("unroll")                                                          \
    for (int nf_ = 0; nf_ < 4; ++nf_)                                          \
        b[nf_] = frag_ld(hB1_, wc64 + nf_ * 16 + l15, lhi);                    \
    BAR();                                                                     \
    __builtin_amdgcn_s_setprio(1);                                             \
    MFMA8(ACCC, 0);                                                            \
    __builtin_amdgcn_s_setprio(0);                                             \
    if (DOST) { STORE1(ACCO, (KT) * 8 + 4); STORE1(ACCO, (KT) * 8 + 5); }      \
    BAR();                                                                     \
    /* phase 3 */                                                              \
    if (DOSTG) stage_halfB(GB + 32, nxt_ + B1OFF, wid, lane);                  \
    a[2] = frag_ld(hA1_, wr64 + 32 + l15, lhi);                                \
    a[3] = frag_ld(hA1_, wr64 + 48 + l15, lhi);                                \
    BAR();                                                                     \
    __builtin_amdgcn_s_setprio(1);                                             \
    MFMA8(ACCC, 2);                                                            \
    __builtin_amdgcn_s_setprio(0);                                             \
    if (DOST) { STORE1(ACCO, (KT) * 8 + 6); STORE1(ACCO, (KT) * 8 + 7); }      \
    if (DOG2) { GATE(G2N); }                                                   \
    BAR();                                                                     \
  }

// 8 K-tiles = one 256x128 output tile. kt0..6 stage kt+1; kt7 stages the NEXT
// output tile's kt0 (A panel reused from k=0, B panel advances).
#define TILE8(ACCC, ACCO, DOST, G1K0, G1M, G2M, BCUR, GB7, KT7G1, KT7DOG2, KT7STG) \
  KTILE(0, ACCC, ACCO, DOST, G1K0,  G2M, 1, Ab +  64, (BCUR) +  64, 1)         \
  KTILE(1, ACCC, ACCO, DOST, G1M,   G2M, 1, Ab + 128, (BCUR) + 128, 1)         \
  KTILE(2, ACCC, ACCO, DOST, G1M,   G2M, 1, Ab + 192, (BCUR) + 192, 1)         \
  KTILE(3, ACCC, ACCO, DOST, G1M,   G2M, 1, Ab + 256, (BCUR) + 256, 1)         \
  KTILE(4, ACCC, ACCO, DOST, G1M,   G2M, 1, Ab + 320, (BCUR) + 320, 1)         \
  KTILE(5, ACCC, ACCO, DOST, G1M,   G2M, 1, Ab + 384, (BCUR) + 384, 1)         \
  KTILE(6, ACCC, ACCO, DOST, G1M,   G2M, 1, Ab + 448, (BCUR) + 448, 1)         \
  KTILE(7, ACCC, ACCO, DOST, KT7G1, G2M, KT7DOG2, Ab, (GB7), KT7STG)

#define ZERO_ACC(A_)                                                           \
  _Pragma("unroll")                                                            \
  for (int z_ = 0; z_ < 4; ++z_)                                               \
    _Pragma("unroll")                                                          \
    for (int w_ = 0; w_ < 4; ++w_)                                             \
      A_[z_][w_] = (f32x4){0.f, 0.f, 0.f, 0.f};

#define PREP_OLD(JOLD)                                                         \
  { const int nold_ = nbase + (JOLD) * 128 + wc64 + l15;                       \
    _Pragma("unroll")                                                          \
    for (int q_ = 0; q_ < 4; ++q_) c2o[q_] = c2[nold_ + q_ * 16];              \
    outOld = out + (size_t)(m0 + wr64 + lhi * 4) * N_COLS + nold_; }

__global__ __launch_bounds__(512, 2) void gemm_kernel(
        const unsigned short* __restrict__ A,   // [M][K] bf16
        const unsigned short* __restrict__ Bt,  // [N][K] bf16 (scaled by 2^-8)
        const float* __restrict__ x2,
        const float* __restrict__ c2,
        float* __restrict__ out) {
    __shared__ unsigned short smem[2][24576];   // 96 KiB

    const int tid  = threadIdx.x;
    const int wid  = tid >> 6;
    const int lane = tid & 63;
    const int wr64 = (wid >> 1) * 64;       // 4 M-waves
    const int wc64 = (wid & 1) * 64;        // 2 N-waves
    const int l15 = lane & 15;
    const int lhi = lane >> 4;

    // XCD-bijective: 256 blocks, 32 consecutive lbid per XCD
    const int bid  = blockIdx.x;
    const int lbid = (bid & 7) * 32 + (bid >> 3);
    const int m0    = (lbid >> 1) * 256;    // 128 m-panels
    const int nbase = (lbid & 1) * 1024;    // 2 n-halves of 8x128 tiles

    const unsigned short* Ab = A + (size_t)m0 * K_DIM;

    f32x4 accA[4][4] = {};
    f32x4 accB[4][4] = {};
    bf16x8 a[4], b[4];
    float c2o[4];
    float* outOld = nullptr;

    // x2 values for this block's 16 row-slots per thread (static-indexed)
    float x2v[16];
    #pragma unroll
    for (int mf = 0; mf < 4; ++mf)
        #pragma unroll
        for (int jj = 0; jj < 4; ++jj)
            x2v[mf * 4 + jj] = x2[m0 + wr64 + mf * 16 + lhi * 4 + jj];

    // prologue: stage tile0 ktile0 (order A0,B0,A1,B1 -> gate A0,B0 => N=3)
    const unsigned short* B0p = Bt + (size_t)nbase * K_DIM;
    stage_halfA(Ab,      smem[0] + A0OFF, wid, lane);
    stage_halfB(B0p,     smem[0] + B0OFF, wid, lane);
    stage_halfA(Ab + 32, smem[0] + A1OFF, wid, lane);
    stage_halfB(B0p + 32, smem[0] + B1OFF, wid, lane);
    GATE(3);
    BAR();

    // tile 0 (cold: no stores). kt7 stages tile1's kt0.
    TILE8(accA, accB, 0, 3, 3, 3, B0p, B0p + 128 * (size_t)K_DIM, 3, 1, 1);

    const unsigned short* Bcur = B0p + 128 * (size_t)K_DIM;  // tile1's B panel
    for (int p = 0; p < 3; ++p) {
        // tile 2p+1: compute accB, store accA (tile 2p)
        PREP_OLD(2 * p);
        ZERO_ACC(accB);
        TILE8(accB, accA, 1, 7, 9, 9, Bcur, Bcur + 128 * (size_t)K_DIM, 9, 1, 1);
        Bcur += 128 * (size_t)K_DIM;
        // tile 2p+2: compute accA, store accB (tile 2p+1)
        PREP_OLD(2 * p + 1);
        ZERO_ACC(accA);
        TILE8(accA, accB, 1, 7, 9, 9, Bcur, Bcur + 128 * (size_t)K_DIM, 9, 1, 1);
        Bcur += 128 * (size_t)K_DIM;
    }
    // tile 7: compute accB, store accA (tile 6); kt7 stages nothing, no G2
    PREP_OLD(6);
    ZERO_ACC(accB);
    TILE8(accB, accA, 1, 7, 9, 9, Bcur, Ab /*unused*/, 6, 0, 0);

    // final epilogue: store tile 7 (accB)
    PREP_OLD(7);
    #pragma unroll
    for (int i = 0; i < 64; ++i) { STORE1(accB, i); }
}

extern "C" void kernel_launch(void* const* d_in, const int* in_sizes, int n_in,
                              void* d_out, int out_size, void* d_ws, size_t ws_size,
                              hipStream_t stream) {
    const float* x  = (const float*)d_in[0];   // [8,4096,512]
    const float* cb = (const float*)d_in[1];   // [1,1,512,2048]
    float* out = (float*)d_out;                // [8,4096,2048]

    char* ws = (char*)d_ws;
    unsigned short* xb  = (unsigned short*)ws;                               // 32 MB
    unsigned short* cbT = (unsigned short*)(ws + (size_t)33554432);          // 2 MB
    float* x2 = (float*)(ws + (size_t)33554432 + 2097152);                   // 128 KB
    float* c2 = (float*)(ws + (size_t)33554432 + 2097152 + 131072);          // 8 KB

    prep_x_kernel<<<M_ROWS / 4, 256, 0, stream>>>(x, xb, x2);
    prep_cb_kernel<<<dim3(16, 32), 256, 0, stream>>>(cb, cbT);
    c2_kernel<<<N_COLS / 64, 256, 0, stream>>>(cb, c2);
    gemm_kernel<<<256, 512, 0, stream>>>(xb, cbT, x2, c2, out);
}

// Round 5
// 122.661 us; speedup vs baseline: 1.6896x; 1.6896x over previous
//
#include <hip/hip_runtime.h>
#include <hip/hip_bf16.h>

// GaussianCodebook: out[b,s,c] = mean_d((x[b,s,d]-cb[d,c])^2)
//                 = x2[m] + c2[n] - (2/D) * dot(x[m,:], cb[:,n])
// B=8 S=4096 D=512 C=2048  -> GEMM M=32768 N=2048 K=512 (bf16 MFMA) + epilogue.
// R5: 128x256 tile, BK=32, 3-deep LDS pipeline (72KB -> 2 blocks/CU, 16
//     waves/CU). Write overlap comes from block TLP (epilogue of one block
//     overlaps MFMA of the co-resident block) -- NOT from stores in the
//     gated vmcnt stream (R4 lesson: stores share vmcnt and stall gates).
//     One barrier + GATE(3) per K-tile; loads 2 tiles ahead, never drained
//     mid-loop. T1 XCD swizzle (A slice 1MB + B 2MB fit per-XCD L2),
//     T2 LDS swizzle, T5 setprio.

typedef __attribute__((ext_vector_type(8))) short bf16x8;
typedef __attribute__((ext_vector_type(4))) float f32x4;

#define M_ROWS 32768
#define K_DIM  512
#define N_COLS 2048

__device__ __forceinline__ unsigned short f2bf(float f) {
    unsigned int u = __float_as_uint(f);
    return (unsigned short)((u + 0x7fffu + ((u >> 16) & 1u)) >> 16);  // RNE
}

__device__ __forceinline__ void gload_lds16(const void* g, void* l) {
    __builtin_amdgcn_global_load_lds(
        (const __attribute__((address_space(1))) unsigned int*)g,
        (__attribute__((address_space(3))) unsigned int*)l,
        16, 0, 0);
}

// ---- prep_x: cast x f32 -> bf16, and x2[m] = mean_d x^2 ----
__global__ __launch_bounds__(256) void prep_x_kernel(const float* __restrict__ x,
                                                     unsigned short* __restrict__ xb,
                                                     float* __restrict__ x2) {
    const int wid = threadIdx.x >> 6;
    const int lane = threadIdx.x & 63;
    const int row = (blockIdx.x << 2) + wid;
    const float4* p4 = reinterpret_cast<const float4*>(x + (size_t)row * K_DIM);
    float4 v0 = p4[lane];
    float4 v1 = p4[lane + 64];
    float ss = v0.x*v0.x + v0.y*v0.y + v0.z*v0.z + v0.w*v0.w
             + v1.x*v1.x + v1.y*v1.y + v1.z*v1.z + v1.w*v1.w;
    union { unsigned short us[4]; uint2 u2; } pa, pb;
    pa.us[0] = f2bf(v0.x); pa.us[1] = f2bf(v0.y); pa.us[2] = f2bf(v0.z); pa.us[3] = f2bf(v0.w);
    pb.us[0] = f2bf(v1.x); pb.us[1] = f2bf(v1.y); pb.us[2] = f2bf(v1.z); pb.us[3] = f2bf(v1.w);
    uint2* dst = reinterpret_cast<uint2*>(xb + (size_t)row * K_DIM);
    dst[lane]      = pa.u2;
    dst[lane + 64] = pb.u2;
    #pragma unroll
    for (int off = 32; off; off >>= 1) ss += __shfl_xor(ss, off);
    if (lane == 0) x2[row] = ss * (1.0f / (float)K_DIM);
}

// ---- prep_cb: transpose cb [K=512][N=2048] f32 -> cbT [N][K] bf16, scaled by 2/D = 2^-8 ----
__global__ __launch_bounds__(256) void prep_cb_kernel(const float* __restrict__ cb,
                                                      unsigned short* __restrict__ cbT) {
    __shared__ float tile[32][65];
    const int k0 = blockIdx.x * 32;
    const int n0 = blockIdx.y * 64;
    const int tx = threadIdx.x & 63;
    const int ty = threadIdx.x >> 6;
    #pragma unroll
    for (int i = 0; i < 8; ++i) {
        const int k = ty + i * 4;
        tile[k][tx] = cb[(size_t)(k0 + k) * N_COLS + n0 + tx];
    }
    __syncthreads();
    const int kc = threadIdx.x & 31;
    const int nr = threadIdx.x >> 5;
    #pragma unroll
    for (int i = 0; i < 8; ++i) {
        const int n = nr + i * 8;
        cbT[(size_t)(n0 + n) * K_DIM + k0 + kc] = f2bf(tile[kc][n] * 0.00390625f);
    }
}

// ---- c2[n] = mean_k cb[k][n]^2 ----
__global__ __launch_bounds__(256) void c2_kernel(const float* __restrict__ cb,
                                                 float* __restrict__ c2) {
    __shared__ float p[4][64];
    const int t = threadIdx.x;
    const int nl = t & 63;
    const int kc = t >> 6;
    const int n = blockIdx.x * 64 + nl;
    float s = 0.0f;
    for (int k = kc * 128; k < kc * 128 + 128; ++k) {
        float v = cb[(size_t)k * N_COLS + n];
        s += v * v;
    }
    p[kc][nl] = s;
    __syncthreads();
    if (t < 64) {
        c2[blockIdx.x * 64 + t] =
            (p[0][t] + p[1][t] + p[2][t] + p[3][t]) * (1.0f / (float)K_DIM);
    }
}

// ======================= 128x256 3-deep-pipeline GEMM =======================
// LDS buffer (shorts): A[128x32] @0 (4096), B[256x32] @4096 (8192) = 24KB; x3 = 72KB.

__device__ __forceinline__ bf16x8 frag_ld(const unsigned short* h, int r, int lhi) {
    const int off = r * 32 + ((lhi ^ ((r >> 1) & 3)) << 3);
    return *reinterpret_cast<const bf16x8*>(&h[off]);
}

#define BAR()  do { asm volatile("" ::: "memory"); \
                    __builtin_amdgcn_s_barrier();  \
                    asm volatile("" ::: "memory"); } while (0)
#define GATE_(n) asm volatile("s_waitcnt vmcnt(" #n ")" ::: "memory")
#define GATE(n) GATE_(n)

__global__ __launch_bounds__(512, 4) void gemm_kernel(
        const unsigned short* __restrict__ A,   // [M][K] bf16
        const unsigned short* __restrict__ Bt,  // [N][K] bf16 (scaled by 2^-8)
        const float* __restrict__ x2,
        const float* __restrict__ c2,
        float* __restrict__ out) {
    __shared__ unsigned short smem[3][12288];   // 72 KiB

    const int tid  = threadIdx.x;
    const int wid  = tid >> 6;
    const int lane = tid & 63;
    const int wr64 = (wid >> 2) * 64;       // 2 M-wave rows
    const int wc64 = (wid & 3) * 64;        // 4 N-wave cols
    const int l15 = lane & 15;
    const int lhi = lane >> 4;

    // T1: XCD-bijective swizzle; 2048 blocks -> 256 consecutive lbid per XCD.
    // lbid = mpanel*8 + npanel: the 8 n-blocks of one m-panel are adjacent
    // (same XCD) -> A panel reused out of L2.
    const int bid  = blockIdx.x;
    const int lbid = (bid & 7) * 256 + (bid >> 3);
    const int m0 = (lbid >> 3) * 128;
    const int n0 = (lbid & 7) * 256;

    const unsigned short* Ab = A  + (size_t)m0 * K_DIM;
    const unsigned short* Bb = Bt + (size_t)n0 * K_DIM;

    // per-lane staging geometry (chunk index -> row, swizzled k-slot)
    const int o16a  = wid * 64 + lane;          // A: 512 chunks
    const int rowa  = o16a >> 2;
    const int sla   = (o16a & 3) ^ ((rowa >> 1) & 3);
    const size_t aoff = (size_t)rowa * K_DIM + sla * 8;
    const int o16b0 = wid * 64 + lane;          // B half 0
    const int rowb0 = o16b0 >> 2;
    const size_t boff0 = (size_t)rowb0 * K_DIM + (((o16b0 & 3) ^ ((rowb0 >> 1) & 3)) * 8);
    const int o16b1 = 512 + wid * 64 + lane;    // B half 1
    const int rowb1 = o16b1 >> 2;
    const size_t boff1 = (size_t)rowb1 * K_DIM + (((o16b1 & 3) ^ ((rowb1 >> 1) & 3)) * 8);

    f32x4 acc[4][4] = {};

#define STAGE(KT, BUF)                                                         \
    do {                                                                       \
        gload_lds16(Ab + aoff  + (KT) * 32, &smem[(BUF)][wid * 512]);          \
        gload_lds16(Bb + boff0 + (KT) * 32, &smem[(BUF)][4096 + wid * 512]);   \
        gload_lds16(Bb + boff1 + (KT) * 32, &smem[(BUF)][8192 + wid * 512]);   \
    } while (0)

    // prologue: tiles 0 and 1 (3 loads each) -> gate tile0 = vmcnt(3)
    STAGE(0, 0);
    STAGE(1, 1);
    GATE(3);
    BAR();

    #pragma unroll
    for (int t = 0; t < 16; ++t) {
        if (t < 14) STAGE(t + 2, (t + 2) % 3);
        const unsigned short* cbuf = smem[t % 3];
        bf16x8 a[4], b[4];
        #pragma unroll
        for (int mf = 0; mf < 4; ++mf)
            a[mf] = frag_ld(cbuf, wr64 + mf * 16 + l15, lhi);
        #pragma unroll
        for (int nf = 0; nf < 4; ++nf)
            b[nf] = frag_ld(cbuf + 4096, wc64 + nf * 16 + l15, lhi);
        __builtin_amdgcn_s_setprio(1);
        #pragma unroll
        for (int mf = 0; mf < 4; ++mf)
            #pragma unroll
            for (int nf = 0; nf < 4; ++nf)
                acc[mf][nf] = __builtin_amdgcn_mfma_f32_16x16x32_bf16(a[mf], b[nf], acc[mf][nf], 0, 0, 0);
        __builtin_amdgcn_s_setprio(0);
        // gate for tile t+1 (read next iter): outstanding after its group =
        // tile t+2's 3 loads (issued this iter) -> vmcnt(3); t=14: drain tail.
        if (t < 14) { GATE(3); } else if (t == 14) { GATE(0); }
        BAR();
    }
#undef STAGE

    // epilogue: C/D layout col = lane&15, row = (lane>>4)*4 + reg
    #pragma unroll
    for (int mf = 0; mf < 4; ++mf) {
        const int mrow = m0 + wr64 + mf * 16 + lhi * 4;
        const float xv0 = x2[mrow + 0];
        const float xv1 = x2[mrow + 1];
        const float xv2 = x2[mrow + 2];
        const float xv3 = x2[mrow + 3];
        #pragma unroll
        for (int nf = 0; nf < 4; ++nf) {
            const int col = n0 + wc64 + nf * 16 + l15;
            const float cv = c2[col];
            float* o = out + (size_t)mrow * N_COLS + col;
            o[0 * N_COLS] = xv0 + cv - acc[mf][nf][0];
            o[1 * N_COLS] = xv1 + cv - acc[mf][nf][1];
            o[2 * N_COLS] = xv2 + cv - acc[mf][nf][2];
            o[3 * N_COLS] = xv3 + cv - acc[mf][nf][3];
        }
    }
}

extern "C" void kernel_launch(void* const* d_in, const int* in_sizes, int n_in,
                              void* d_out, int out_size, void* d_ws, size_t ws_size,
                              hipStream_t stream) {
    const float* x  = (const float*)d_in[0];   // [8,4096,512]
    const float* cb = (const float*)d_in[1];   // [1,1,512,2048]
    float* out = (float*)d_out;                // [8,4096,2048]

    char* ws = (char*)d_ws;
    unsigned short* xb  = (unsigned short*)ws;                               // 32 MB
    unsigned short* cbT = (unsigned short*)(ws + (size_t)33554432);          // 2 MB
    float* x2 = (float*)(ws + (size_t)33554432 + 2097152);                   // 128 KB
    float* c2 = (float*)(ws + (size_t)33554432 + 2097152 + 131072);          // 8 KB

    prep_x_kernel<<<M_ROWS / 4, 256, 0, stream>>>(x, xb, x2);
    prep_cb_kernel<<<dim3(16, 32), 256, 0, stream>>>(cb, cbT);
    c2_kernel<<<N_COLS / 64, 256, 0, stream>>>(cb, c2);
    gemm_kernel<<<dim3((M_ROWS / 128) * (N_COLS / 256)), 512, 0, stream>>>(xb, cbT, x2, c2, out);
}